// Round 1
// baseline (3623.957 us; speedup 1.0000x reference)
//
#include <hip/hip_runtime.h>

#define EPSV 1e-5f
#define CK 8

// ---------------- weight repack ----------------
// w1 [512][128][3][3] -> w1r [(ci*9+t)*512 + c*4 + q]  where co = q*128+c
// ws,w2 [64][128][3][3] -> [(ci*9+t)*64 + co]
__global__ void repack_kernel(const float* __restrict__ w1, const float* __restrict__ ws,
                              const float* __restrict__ w2, float* __restrict__ w1r,
                              float* __restrict__ wsr, float* __restrict__ w2r) {
    int i = blockIdx.x * 256 + threadIdx.x;
    if (i < 512 * 128 * 9) {
        int co = i / (128 * 9);
        int r  = i - co * (128 * 9);
        int ci = r / 9;
        int t  = r - ci * 9;
        w1r[(ci * 9 + t) * 512 + ((co & 127) << 2) + (co >> 7)] = w1[i];
    }
    if (i < 64 * 128 * 9) {
        int co = i / (128 * 9);
        int r  = i - co * (128 * 9);
        int ci = r / 9;
        int t  = r - ci * 9;
        wsr[(ci * 9 + t) * 64 + co] = ws[i];
        w2r[(ci * 9 + t) * 64 + co] = w2[i];
    }
}

// ---------------- conv1 + BN + ReLU + Haar IDWT ----------------
// in x (16,128,64,64); out idwt (16,128,128,128)
// block: 256 thr; tile 32x32; each thread: 4 y-positions, 4 base c x 4 quadrants
__global__ __launch_bounds__(256, 2)
void conv1_idwt_kernel(const float* __restrict__ x, const float* __restrict__ w1r,
                       const float* __restrict__ b1, const float* __restrict__ g1,
                       const float* __restrict__ be1, const float* __restrict__ m1,
                       const float* __restrict__ v1, float* __restrict__ idwt) {
    const int cg   = blockIdx.x;            // 32 groups of 4 base channels
    const int tile = blockIdx.y;            // 2x2 tiles of 32x32 over 64x64
    const int n    = blockIdx.z;
    const int c0   = cg * 4;
    const int ty0  = (tile >> 1) * 32;
    const int tx0  = (tile & 1) * 32;
    const int tid  = threadIdx.x;
    const int tx   = tid & 31;
    const int py0  = (tid >> 5) * 4;

    __shared__ float lt[CK][34][34];

    float acc[16][4];
#pragma unroll
    for (int w = 0; w < 16; ++w)
#pragma unroll
        for (int i = 0; i < 4; ++i) acc[w][i] = 0.f;

    for (int ci0 = 0; ci0 < 128; ci0 += CK) {
        __syncthreads();
        for (int e = tid; e < CK * 34 * 34; e += 256) {
            int ci = e / 1156;
            int r  = e - ci * 1156;
            int yy = r / 34;
            int xx = r - yy * 34;
            int gy = ty0 - 1 + yy, gx = tx0 - 1 + xx;
            float vv = 0.f;
            if ((unsigned)gy < 64u && (unsigned)gx < 64u)
                vv = x[(((size_t)n * 128 + ci0 + ci) * 64 + gy) * 64 + gx];
            lt[ci][yy][xx] = vv;
        }
        __syncthreads();
#pragma unroll
        for (int ci = 0; ci < CK; ++ci) {
            float inz[6][3];
#pragma unroll
            for (int i = 0; i < 6; ++i)
#pragma unroll
                for (int j = 0; j < 3; ++j)
                    inz[i][j] = lt[ci][py0 + i][tx + j];
            const float4* wp4 = (const float4*)(w1r + (size_t)((ci0 + ci) * 9) * 512 + c0 * 4);
#pragma unroll
            for (int t = 0; t < 9; ++t) {
                float4 wa = wp4[t * 128 + 0];
                float4 wb = wp4[t * 128 + 1];
                float4 wc = wp4[t * 128 + 2];
                float4 wd = wp4[t * 128 + 3];
                const int ky = t / 3, kx = t - (t / 3) * 3;
                float wv[16] = {wa.x, wa.y, wa.z, wa.w, wb.x, wb.y, wb.z, wb.w,
                                wc.x, wc.y, wc.z, wc.w, wd.x, wd.y, wd.z, wd.w};
#pragma unroll
                for (int w = 0; w < 16; ++w)
#pragma unroll
                    for (int i = 0; i < 4; ++i)
                        acc[w][i] += wv[w] * inz[ky + i][kx];
            }
        }
    }

    // epilogue: BN+ReLU per quadrant channel, then 2x2 Haar butterfly
#pragma unroll
    for (int cc = 0; cc < 4; ++cc) {
        const int c = c0 + cc;
        float sc[4], sh[4];
#pragma unroll
        for (int q = 0; q < 4; ++q) {
            int co    = q * 128 + c;
            float inv = g1[co] / sqrtf(v1[co] + EPSV);
            sc[q]     = inv;
            sh[q]     = b1[co] * inv + be1[co] - m1[co] * inv;
        }
#pragma unroll
        for (int i = 0; i < 4; ++i) {
            float a  = fmaxf(acc[cc * 4 + 0][i] * sc[0] + sh[0], 0.f);
            float hh = fmaxf(acc[cc * 4 + 1][i] * sc[1] + sh[1], 0.f);
            float vv = fmaxf(acc[cc * 4 + 2][i] * sc[2] + sh[2], 0.f);
            float dd = fmaxf(acc[cc * 4 + 3][i] * sc[3] + sh[3], 0.f);
            float p00 = (a + hh + vv + dd) * 0.5f;
            float p01 = (a + hh - vv - dd) * 0.5f;
            float p10 = (a - hh + vv - dd) * 0.5f;
            float p11 = (a - hh - vv + dd) * 0.5f;
            int oy = (ty0 + py0 + i) * 2, ox = (tx0 + tx) * 2;
            size_t base = (((size_t)n * 128 + c) * 128 + oy) * 128 + ox;
            *(float2*)&idwt[base]       = make_float2(p00, p01);
            *(float2*)&idwt[base + 128] = make_float2(p10, p11);
        }
    }
}

// ---------------- generic 128ch -> 64ch conv + BN + ReLU over 128x128 ----------------
// channels [0,C0) come from in0 (C0-channel tensor), [C0,128) from in1 (128-C0 channels)
__global__ __launch_bounds__(256, 2)
void conv_bn_kernel(const float* __restrict__ in0, const float* __restrict__ in1,
                    const int C0, const float* __restrict__ wr,
                    const float* __restrict__ bb, const float* __restrict__ gg,
                    const float* __restrict__ bee, const float* __restrict__ mm,
                    const float* __restrict__ vvp, float* __restrict__ out) {
    const int cg   = blockIdx.x;           // 4 groups of 16 co
    const int tile = blockIdx.y;           // 4x4 tiles of 32x32 over 128x128
    const int n    = blockIdx.z;
    const int c0   = cg * 16;
    const int ty0  = (tile >> 2) * 32;
    const int tx0  = (tile & 3) * 32;
    const int tid  = threadIdx.x;
    const int tx   = tid & 31;
    const int py0  = (tid >> 5) * 4;

    __shared__ float lt[CK][34][34];

    float acc[16][4];
#pragma unroll
    for (int w = 0; w < 16; ++w)
#pragma unroll
        for (int i = 0; i < 4; ++i) acc[w][i] = 0.f;

    for (int ci0 = 0; ci0 < 128; ci0 += CK) {
        const float* src;
        int cb, CS;
        if (ci0 < C0) { src = in0; cb = ci0;      CS = C0; }
        else          { src = in1; cb = ci0 - C0; CS = 128 - C0; }
        __syncthreads();
        for (int e = tid; e < CK * 34 * 34; e += 256) {
            int ci = e / 1156;
            int r  = e - ci * 1156;
            int yy = r / 34;
            int xx = r - yy * 34;
            int gy = ty0 - 1 + yy, gx = tx0 - 1 + xx;
            float vv = 0.f;
            if ((unsigned)gy < 128u && (unsigned)gx < 128u)
                vv = src[(((size_t)n * CS + cb + ci) * 128 + gy) * 128 + gx];
            lt[ci][yy][xx] = vv;
        }
        __syncthreads();
#pragma unroll
        for (int ci = 0; ci < CK; ++ci) {
            float inz[6][3];
#pragma unroll
            for (int i = 0; i < 6; ++i)
#pragma unroll
                for (int j = 0; j < 3; ++j)
                    inz[i][j] = lt[ci][py0 + i][tx + j];
            const float4* wp4 = (const float4*)(wr + (size_t)((ci0 + ci) * 9) * 64 + c0);
#pragma unroll
            for (int t = 0; t < 9; ++t) {
                float4 wa = wp4[t * 16 + 0];
                float4 wb = wp4[t * 16 + 1];
                float4 wc = wp4[t * 16 + 2];
                float4 wd = wp4[t * 16 + 3];
                const int ky = t / 3, kx = t - (t / 3) * 3;
                float wv[16] = {wa.x, wa.y, wa.z, wa.w, wb.x, wb.y, wb.z, wb.w,
                                wc.x, wc.y, wc.z, wc.w, wd.x, wd.y, wd.z, wd.w};
#pragma unroll
                for (int w = 0; w < 16; ++w)
#pragma unroll
                    for (int i = 0; i < 4; ++i)
                        acc[w][i] += wv[w] * inz[ky + i][kx];
            }
        }
    }

#pragma unroll
    for (int w = 0; w < 16; ++w) {
        const int co = c0 + w;
        float inv = gg[co] / sqrtf(vvp[co] + EPSV);
        float sh  = bb[co] * inv + bee[co] - mm[co] * inv;
#pragma unroll
        for (int i = 0; i < 4; ++i) {
            float r = fmaxf(acc[w][i] * inv + sh, 0.f);
            out[(((size_t)n * 64 + co) * 128 + ty0 + py0 + i) * 128 + tx0 + tx] = r;
        }
    }
}

extern "C" void kernel_launch(void* const* d_in, const int* in_sizes, int n_in,
                              void* d_out, int out_size, void* d_ws, size_t ws_size,
                              hipStream_t stream) {
    const float* x   = (const float*)d_in[0];
    const float* s   = (const float*)d_in[1];
    const float* w1  = (const float*)d_in[2];
    const float* b1  = (const float*)d_in[3];
    const float* g1  = (const float*)d_in[4];
    const float* be1 = (const float*)d_in[5];
    const float* m1  = (const float*)d_in[6];
    const float* v1  = (const float*)d_in[7];
    const float* wsw = (const float*)d_in[8];
    const float* bs  = (const float*)d_in[9];
    const float* gs  = (const float*)d_in[10];
    const float* bes = (const float*)d_in[11];
    const float* ms  = (const float*)d_in[12];
    const float* vs  = (const float*)d_in[13];
    const float* w2  = (const float*)d_in[14];
    const float* b2  = (const float*)d_in[15];
    const float* g2  = (const float*)d_in[16];
    const float* be2 = (const float*)d_in[17];
    const float* m2  = (const float*)d_in[18];
    const float* v2  = (const float*)d_in[19];
    float* out = (float*)d_out;

    char* wsp = (char*)d_ws;
    // layout: idwt 134,217,728 | s_out 67,108,864 | w1r 2,359,296 | wsr 294,912 | w2r 294,912
    float* idwt = (float*)(wsp);
    float* sout = (float*)(wsp + 134217728);
    float* w1r  = (float*)(wsp + 134217728 + 67108864);
    float* wsr  = (float*)(wsp + 134217728 + 67108864 + 2359296);
    float* w2r  = (float*)(wsp + 134217728 + 67108864 + 2359296 + 294912);

    repack_kernel<<<dim3((512 * 128 * 9 + 255) / 256), dim3(256), 0, stream>>>(
        w1, wsw, w2, w1r, wsr, w2r);

    // conv1 + bn + relu + idwt  -> idwt buffer
    conv1_idwt_kernel<<<dim3(32, 4, 16), dim3(256), 0, stream>>>(
        x, w1r, b1, g1, be1, m1, v1, idwt);

    // convS + bn + relu -> sout   (input: idwt, all 128 channels from in0)
    conv_bn_kernel<<<dim3(4, 16, 16), dim3(256), 0, stream>>>(
        idwt, idwt, 128, wsr, bs, gs, bes, ms, vs, sout);

    // conv2 + bn + relu -> out    (input: concat[s(64ch), sout(64ch)])
    conv_bn_kernel<<<dim3(4, 16, 16), dim3(256), 0, stream>>>(
        s, sout, 64, w2r, b2, g2, be2, m2, v2, out);
}

// Round 2
// 232.664 us; speedup vs baseline: 15.5759x; 15.5759x over previous
//
#include <hip/hip_runtime.h>
#include <hip/hip_bf16.h>

typedef __attribute__((ext_vector_type(8))) short short8;
typedef __attribute__((ext_vector_type(4))) float f32x4;
typedef unsigned short u16;

#define EPSV 1e-5f

__device__ __forceinline__ u16 f2bf(float f) {
    __hip_bfloat16 h = __float2bfloat16(f);
    return *reinterpret_cast<u16*>(&h);
}

// ---------------- NCHW fp32 -> [C/32][N][H][W][32] bf16 ----------------
__global__ void cvt_kernel(const float* __restrict__ src, u16* __restrict__ dst,
                           int C, int H, int W, int units) {
    int u = blockIdx.x * 256 + threadIdx.x;
    if (u >= units) return;
    int kb = u & 3;
    int p  = u >> 2;
    int x  = p % W;  p /= W;
    int y  = p % H;  p /= H;
    int n  = p & 15;
    int cc = p >> 4;
    short8 v;
#pragma unroll
    for (int j = 0; j < 8; ++j)
        v[j] = (short)f2bf(src[(((size_t)n * C + cc * 32 + kb * 8 + j) * H + y) * W + x]);
    *(short8*)(dst + ((((size_t)cc * 16 + n) * H + y) * W + x) * 32 + kb * 8) = v;
}

// ---------------- weight repack: fragment-linear ----------------
// conv1: w1[512][128][3][3]; tiles: cc(4) x bt(8: q*2+h); unit=(((cc*8+bt)*9+t)*4+ciC)*64+l
__global__ void repack_w1_kernel(const float* __restrict__ w1, u16* __restrict__ wf) {
    int u = blockIdx.x * 256 + threadIdx.x;
    if (u >= 4 * 8 * 9 * 4 * 64) return;
    int l = u & 63;
    int r = u >> 6;
    int ciC = r & 3;  r >>= 2;
    int t   = r % 9;  r /= 9;
    int bt  = r & 7;
    int cc  = r >> 3;
    int co  = (bt >> 1) * 128 + cc * 32 + (bt & 1) * 16 + (l & 15);
    int ci0 = ciC * 32 + (l >> 4) * 8;
    short8 v;
#pragma unroll
    for (int e = 0; e < 8; ++e)
        v[e] = (short)f2bf(w1[((size_t)co * 128 + ci0 + e) * 9 + t]);
    *(short8*)(wf + (size_t)u * 8) = v;
}

// generic 64-co weights: tiles bt(4); unit=(((bt*9+t)*4+ciC)*64+l
__global__ void repack_wg_kernel(const float* __restrict__ w, u16* __restrict__ wf) {
    int u = blockIdx.x * 256 + threadIdx.x;
    if (u >= 4 * 9 * 4 * 64) return;
    int l = u & 63;
    int r = u >> 6;
    int ciC = r & 3;  r >>= 2;
    int t   = r % 9;
    int bt  = r / 9;
    int co  = bt * 16 + (l & 15);
    int ci0 = ciC * 32 + (l >> 4) * 8;
    short8 v;
#pragma unroll
    for (int e = 0; e < 8; ++e)
        v[e] = (short)f2bf(w[((size_t)co * 128 + ci0 + e) * 9 + t]);
    *(short8*)(wf + (size_t)u * 8) = v;
}

// ---------------- conv1 + BN + ReLU + Haar IDWT (MFMA) ----------------
// in xb [4][16][64][64][32] bf16; out idwt [4][16][128][128][32] bf16
// block: 256 thr (4 waves), tile m=128 (16x x 8y), co-tile = 4q x 32c (cc chunk)
__global__ __launch_bounds__(256, 2)
void conv1_mfma_kernel(const u16* __restrict__ inb, const u16* __restrict__ wf,
                       const float* __restrict__ bb, const float* __restrict__ gg,
                       const float* __restrict__ bee, const float* __restrict__ mm,
                       const float* __restrict__ vv, u16* __restrict__ ob) {
    const int tile = blockIdx.x;              // 4x x 8y = 32
    const int cc   = blockIdx.y;              // 4 base-c chunks
    const int n    = blockIdx.z;
    const int x0   = (tile & 3) * 16;
    const int y0   = (tile >> 2) * 8;
    const int tid  = threadIdx.x;
    const int lane = tid & 63;
    const int wid  = tid >> 6;
    const int wm   = wid >> 1;                // m half (rows wm*4..wm*4+3)
    const int wc   = wid & 1;                 // c16 half
    const int kb   = lane >> 4;
    const int xl   = lane & 15;

    __shared__ float4 lds4[720];              // 10 x 18 x 32 bf16, swizzled
    const short8* ldsr = (const short8*)lds4;

    f32x4 acc[4][4];                          // [row j][quadrant q]
#pragma unroll
    for (int j = 0; j < 4; ++j)
#pragma unroll
        for (int q = 0; q < 4; ++q) acc[j][q] = (f32x4){0.f, 0.f, 0.f, 0.f};

    float4 sreg[3];
    auto load_stage = [&](int ciC) {
#pragma unroll
        for (int p = 0; p < 3; ++p) {
            int e = p * 256 + tid;
            float4 v = make_float4(0.f, 0.f, 0.f, 0.f);
            if (e < 720) {
                int pix = e >> 2, ke = e & 3;
                int yy = pix / 18;
                int xx = pix - yy * 18;
                int gy = y0 - 1 + yy, gx = x0 - 1 + xx;
                if ((unsigned)gy < 64u && (unsigned)gx < 64u)
                    v = *(const float4*)(inb + ((((size_t)ciC * 16 + n) * 64 + gy) * 64 + gx) * 32 + ke * 8);
            }
            sreg[p] = v;
        }
    };
    auto write_stage = [&]() {
#pragma unroll
        for (int p = 0; p < 3; ++p) {
            int e = p * 256 + tid;
            if (e < 720) lds4[e ^ ((e >> 2) & 7)] = sreg[p];
        }
    };

    load_stage(0);
    for (int ciC = 0; ciC < 4; ++ciC) {
        write_stage();
        __syncthreads();
        if (ciC < 3) load_stage(ciC + 1);
#pragma unroll
        for (int t = 0; t < 9; ++t) {
            const int dy = t / 3, dx = t - (t / 3) * 3;
            short8 a[4], b[4];
#pragma unroll
            for (int j = 0; j < 4; ++j) {
                int pix = (wm * 4 + j + dy) * 18 + xl + dx;
                int e = pix * 4 + kb;
                a[j] = ldsr[e ^ ((e >> 2) & 7)];
            }
#pragma unroll
            for (int q = 0; q < 4; ++q) {
                int bt = q * 2 + wc;
                b[q] = *(const short8*)(wf + ((size_t)(((cc * 8 + bt) * 9 + t) * 4 + ciC) * 64 + lane) * 8);
            }
#pragma unroll
            for (int j = 0; j < 4; ++j)
#pragma unroll
                for (int q = 0; q < 4; ++q)
                    acc[j][q] = __builtin_amdgcn_mfma_f32_16x16x32_bf16(a[j], b[q], acc[j][q], 0, 0, 0);
        }
        __syncthreads();
    }

    // epilogue: BN+ReLU per quadrant, Haar butterfly, store NHWC-c32 bf16
    float invq[4], shq[4];
#pragma unroll
    for (int q = 0; q < 4; ++q) {
        int co  = q * 128 + cc * 32 + wc * 16 + xl;
        float inv = gg[co] / sqrtf(vv[co] + EPSV);
        invq[q] = inv;
        shq[q]  = bb[co] * inv + bee[co] - mm[co] * inv;
    }
    const int c32 = wc * 16 + xl;
#pragma unroll
    for (int j = 0; j < 4; ++j) {
        int y = y0 + wm * 4 + j;
#pragma unroll
        for (int i = 0; i < 4; ++i) {
            float A_ = fmaxf(acc[j][0][i] * invq[0] + shq[0], 0.f);
            float H_ = fmaxf(acc[j][1][i] * invq[1] + shq[1], 0.f);
            float V_ = fmaxf(acc[j][2][i] * invq[2] + shq[2], 0.f);
            float D_ = fmaxf(acc[j][3][i] * invq[3] + shq[3], 0.f);
            float p00 = (A_ + H_ + V_ + D_) * 0.5f;
            float p01 = (A_ + H_ - V_ - D_) * 0.5f;
            float p10 = (A_ - H_ + V_ - D_) * 0.5f;
            float p11 = (A_ - H_ - V_ + D_) * 0.5f;
            int oy = 2 * y, ox = 2 * (x0 + kb * 4 + i);
            size_t base = ((((size_t)cc * 16 + n) * 128 + oy) * 128 + ox) * 32 + c32;
            ob[base]            = f2bf(p00);
            ob[base + 32]       = f2bf(p01);
            ob[base + 128 * 32] = f2bf(p10);
            ob[base + 128 * 32 + 32] = f2bf(p11);
        }
    }
}

// ---------------- generic 128ci -> 64co conv + BN + ReLU (MFMA), H=W=128 ----------------
template <bool FP32OUT>
__global__ __launch_bounds__(256, 2)
void convg_mfma_kernel(const u16* __restrict__ inb, const u16* __restrict__ wf,
                       const float* __restrict__ bb, const float* __restrict__ gg,
                       const float* __restrict__ bee, const float* __restrict__ mm,
                       const float* __restrict__ vv, u16* __restrict__ ob,
                       float* __restrict__ of) {
    const int tile = blockIdx.x;              // 8x x 16y = 128
    const int n    = blockIdx.y;
    const int x0   = (tile & 7) * 16;
    const int y0   = (tile >> 3) * 8;
    const int tid  = threadIdx.x;
    const int lane = tid & 63;
    const int wid  = tid >> 6;
    const int wm   = wid >> 1;
    const int wc   = wid & 1;                 // co16 pair: wc*2, wc*2+1
    const int kb   = lane >> 4;
    const int xl   = lane & 15;

    __shared__ float4 lds4[720];
    const short8* ldsr = (const short8*)lds4;

    f32x4 acc[4][2];
#pragma unroll
    for (int j = 0; j < 4; ++j)
#pragma unroll
        for (int cb = 0; cb < 2; ++cb) acc[j][cb] = (f32x4){0.f, 0.f, 0.f, 0.f};

    float4 sreg[3];
    auto load_stage = [&](int ciC) {
#pragma unroll
        for (int p = 0; p < 3; ++p) {
            int e = p * 256 + tid;
            float4 v = make_float4(0.f, 0.f, 0.f, 0.f);
            if (e < 720) {
                int pix = e >> 2, ke = e & 3;
                int yy = pix / 18;
                int xx = pix - yy * 18;
                int gy = y0 - 1 + yy, gx = x0 - 1 + xx;
                if ((unsigned)gy < 128u && (unsigned)gx < 128u)
                    v = *(const float4*)(inb + ((((size_t)ciC * 16 + n) * 128 + gy) * 128 + gx) * 32 + ke * 8);
            }
            sreg[p] = v;
        }
    };
    auto write_stage = [&]() {
#pragma unroll
        for (int p = 0; p < 3; ++p) {
            int e = p * 256 + tid;
            if (e < 720) lds4[e ^ ((e >> 2) & 7)] = sreg[p];
        }
    };

    load_stage(0);
    for (int ciC = 0; ciC < 4; ++ciC) {
        write_stage();
        __syncthreads();
        if (ciC < 3) load_stage(ciC + 1);
#pragma unroll
        for (int t = 0; t < 9; ++t) {
            const int dy = t / 3, dx = t - (t / 3) * 3;
            short8 a[4], b[2];
#pragma unroll
            for (int j = 0; j < 4; ++j) {
                int pix = (wm * 4 + j + dy) * 18 + xl + dx;
                int e = pix * 4 + kb;
                a[j] = ldsr[e ^ ((e >> 2) & 7)];
            }
#pragma unroll
            for (int cb = 0; cb < 2; ++cb) {
                int bt = wc * 2 + cb;
                b[cb] = *(const short8*)(wf + ((size_t)((bt * 9 + t) * 4 + ciC) * 64 + lane) * 8);
            }
#pragma unroll
            for (int j = 0; j < 4; ++j)
#pragma unroll
                for (int cb = 0; cb < 2; ++cb)
                    acc[j][cb] = __builtin_amdgcn_mfma_f32_16x16x32_bf16(a[j], b[cb], acc[j][cb], 0, 0, 0);
        }
        __syncthreads();
    }

#pragma unroll
    for (int cb = 0; cb < 2; ++cb) {
        int co = (wc * 2 + cb) * 16 + xl;
        float inv = gg[co] / sqrtf(vv[co] + EPSV);
        float sh  = bb[co] * inv + bee[co] - mm[co] * inv;
#pragma unroll
        for (int j = 0; j < 4; ++j) {
            int y = y0 + wm * 4 + j;
#pragma unroll
            for (int i = 0; i < 4; ++i) {
                float val = fmaxf(acc[j][cb][i] * inv + sh, 0.f);
                int xg = x0 + kb * 4 + i;
                if (FP32OUT) {
                    of[(((size_t)n * 64 + co) * 128 + y) * 128 + xg] = val;
                } else {
                    ob[((((size_t)(co >> 5) * 16 + n) * 128 + y) * 128 + xg) * 32 + (co & 31)] = f2bf(val);
                }
            }
        }
    }
}

extern "C" void kernel_launch(void* const* d_in, const int* in_sizes, int n_in,
                              void* d_out, int out_size, void* d_ws, size_t ws_size,
                              hipStream_t stream) {
    const float* x   = (const float*)d_in[0];
    const float* s   = (const float*)d_in[1];
    const float* w1  = (const float*)d_in[2];
    const float* b1  = (const float*)d_in[3];
    const float* g1  = (const float*)d_in[4];
    const float* be1 = (const float*)d_in[5];
    const float* m1  = (const float*)d_in[6];
    const float* v1  = (const float*)d_in[7];
    const float* wsw = (const float*)d_in[8];
    const float* bs  = (const float*)d_in[9];
    const float* gs  = (const float*)d_in[10];
    const float* bes = (const float*)d_in[11];
    const float* ms  = (const float*)d_in[12];
    const float* vs  = (const float*)d_in[13];
    const float* w2  = (const float*)d_in[14];
    const float* b2  = (const float*)d_in[15];
    const float* g2  = (const float*)d_in[16];
    const float* be2 = (const float*)d_in[17];
    const float* m2  = (const float*)d_in[18];
    const float* v2  = (const float*)d_in[19];
    float* out = (float*)d_out;

    char* wsp = (char*)d_ws;
    // bytes: xb 16,777,216 | idwt 67,108,864 | cat 67,108,864 | wf1 1,179,648 | wfS 147,456 | wf2 147,456
    u16* xb   = (u16*)(wsp);
    u16* idwt = (u16*)(wsp + 16777216);
    u16* cat  = (u16*)(wsp + 16777216 + 67108864);
    u16* wf1  = (u16*)(wsp + 16777216 + 67108864 + 67108864);
    u16* wfS  = (u16*)(wsp + 16777216 + 67108864 + 67108864 + 1179648);
    u16* wf2  = (u16*)(wsp + 16777216 + 67108864 + 67108864 + 1179648 + 147456);

    // preprocessing
    cvt_kernel<<<dim3(4096), dim3(256), 0, stream>>>(x, xb, 128, 64, 64, 1048576);
    cvt_kernel<<<dim3(8192), dim3(256), 0, stream>>>(s, cat, 64, 128, 128, 2097152);
    repack_w1_kernel<<<dim3(288), dim3(256), 0, stream>>>(w1, wf1);
    repack_wg_kernel<<<dim3(36), dim3(256), 0, stream>>>(wsw, wfS);
    repack_wg_kernel<<<dim3(36), dim3(256), 0, stream>>>(w2, wf2);

    // conv1 + BN + ReLU + IDWT -> idwt (NHWC-c32 bf16)
    conv1_mfma_kernel<<<dim3(32, 4, 16), dim3(256), 0, stream>>>(
        xb, wf1, b1, g1, be1, m1, v1, idwt);

    // convS + BN + ReLU -> cat chunks 2,3
    convg_mfma_kernel<false><<<dim3(128, 16), dim3(256), 0, stream>>>(
        idwt, wfS, bs, gs, bes, ms, vs, cat + (size_t)2 * 16 * 128 * 128 * 32, nullptr);

    // conv2 + BN + ReLU -> d_out (fp32 NCHW)
    convg_mfma_kernel<true><<<dim3(128, 16), dim3(256), 0, stream>>>(
        cat, wf2, b2, g2, be2, m2, v2, nullptr, out);
}